// Round 6
// baseline (154.792 us; speedup 1.0000x reference)
//
#include <hip/hip_runtime.h>
#include <hip/hip_fp16.h>
#include <math.h>

#define FEATD 128
#define NNODES 10000
#define NBATCH 4
#define NROWS (NBATCH*NNODES)   // 40000

// ws layout (float/int slots, 4B each)
#define OFF_I1   0                     // 1/sigma1
#define OFF_W1L  8                     // w1last normalized [32] f32
#define OFF_W2   64                    // W2 normalized [32*32] f32 (fallback)
#define OFF_W3   1088                  // W3 normalized [32] f32
#define OFF_W2H  1120                  // W2 normalized half2 [512 uint slots]
#define OFF_SEG  1664                  // int segStart[5]
#define OFF_BC   1680                  // int blockCounts[256*4]
#define OFF_BASE 2704                  // int blockBases[256*4]
#define OFF_P16  4096                  // P16 raw proj [40000][64] half (5.12 MB)
#define P16_FLOATS (NROWS*64/2)        // 1,280,000 float slots
#define OFF_F16  (OFF_P16 + P16_FLOATS) // feat16 [40000][128] half (10.24 MB)
#define F16_FLOATS (NROWS*FEATD/2)     // 2,560,000 float slots
#define OFF_REC  (OFF_F16 + F16_FLOATS) // int4 records [E] (16B each)
#define OFF_FBWT OFF_P16               // fallback: normalized Wt[128][64] f32

typedef _Float16 h2 __attribute__((ext_vector_type(2)));
union U32H2 { unsigned u; h2 h; };
union U4H2  { uint4 u; h2 h[4]; };

#if defined(__has_builtin)
#if __has_builtin(__builtin_amdgcn_fdot2)
#define HAVE_FDOT2 1
#endif
#endif

__device__ __forceinline__ float fdot2f(h2 a, h2 b, float c) {
#ifdef HAVE_FDOT2
  return __builtin_amdgcn_fdot2(a, b, c, false);
#else
  return c + (float)a[0] * (float)b[0] + (float)a[1] * (float)b[1];
#endif
}

// ------------- spectral sigma: exact reference power iteration, 2 barriers/iter -------------
template <int M, int K>
__device__ float spectral_sigma_t(const float* __restrict__ Wg,
                                  float* sW, float* u, float* v, volatile float* red) {
  int tid = threadIdx.x;
  int wid = tid >> 6, lid = tid & 63;
  int j8 = tid >> 3, l8 = tid & 7;
  for (int i = tid; i < M * K; i += 256) sW[i] = Wg[i];
  if (tid < M) u[tid] = 1.0f;
  __syncthreads();
  float invu = 1.0f / sqrtf((float)M);
  float invv = 0.f;

  for (int it = 0; it < 5; ++it) {
    float p = 0.f;
    for (int k = tid; k < K; k += 256) {
      float a = 0.f;
      #pragma unroll
      for (int j = 0; j < M; ++j) a += sW[j * K + k] * u[j];
      a *= invu;
      v[k] = a;
      p += a * a;
    }
    #pragma unroll
    for (int off = 1; off < 64; off <<= 1) p += __shfl_xor(p, off, 64);
    if (lid == 0) red[wid] = p;
    __syncthreads();
    p = red[0] + red[1] + red[2] + red[3];
    invv = 1.0f / (sqrtf(p) + 1e-12f);

    float a = 0.f;
    if (j8 < M) {
      #pragma unroll
      for (int k = l8; k < K; k += 8) a += sW[j8 * K + k] * v[k];
      a *= invv;
    }
    a += __shfl_xor(a, 1, 64);
    a += __shfl_xor(a, 2, 64);
    a += __shfl_xor(a, 4, 64);
    float q = 0.f;
    if (j8 < M && l8 == 0) { u[j8] = a; q = a * a; }
    #pragma unroll
    for (int off = 1; off < 64; off <<= 1) q += __shfl_xor(q, off, 64);
    if (lid == 0) red[4 + wid] = q;
    __syncthreads();
    q = red[4] + red[5] + red[6] + red[7];
    invu = 1.0f / (sqrtf(q) + 1e-12f);
  }

  float a = 0.f;
  if (j8 < M) {
    #pragma unroll
    for (int k = l8; k < K; k += 8) a += sW[j8 * K + k] * v[k];
  }
  a += __shfl_xor(a, 1, 64);
  a += __shfl_xor(a, 2, 64);
  a += __shfl_xor(a, 4, 64);
  float s = (j8 < M && l8 == 0) ? a * u[j8] : 0.f;
  #pragma unroll
  for (int off = 1; off < 64; off <<= 1) s += __shfl_xor(s, off, 64);
  if (lid == 0) red[wid] = s;
  __syncthreads();
  float sig = (red[0] + red[1] + red[2] + red[3]) * invu * invv;
  __syncthreads();
  return sig;
}

// ---------------- fused prep kernel ----------------
__global__ __launch_bounds__(256) void prep_kernel(const float* __restrict__ feat,
                                                   const float* __restrict__ W1,
                                                   const float* __restrict__ W2,
                                                   const float* __restrict__ W3,
                                                   float* __restrict__ ws,
                                                   int doF16) {
  __shared__ float sA[32 * 257];
  __shared__ float u[32], v[257];
  __shared__ float red[8];
  int tid = threadIdx.x;

  if (blockIdx.x == 0) {
    float sig1 = spectral_sigma_t<32, 257>(W1, sA, u, v, red);
    float i1 = 1.0f / sig1;
    if (tid == 0) ws[OFF_I1] = i1;
    for (int j = tid; j < 32; j += 256) ws[OFF_W1L + j] = sA[j * 257 + 256] * i1;
    __syncthreads();
    float sig2 = spectral_sigma_t<32, 32>(W2, sA, u, v, red);
    float i2 = 1.0f / sig2;
    for (int idx = tid; idx < 1024; idx += 256) ws[OFF_W2 + idx] = sA[idx] * i2;
    unsigned* w2h = (unsigned*)(ws + OFF_W2H);
    for (int idx = tid; idx < 512; idx += 256) {
      int j = idx >> 4, q = idx & 15;
      U32H2 pk;
      pk.h[0] = (_Float16)(sA[j * 32 + 2 * q] * i2);
      pk.h[1] = (_Float16)(sA[j * 32 + 2 * q + 1] * i2);
      w2h[idx] = pk.u;
    }
    __syncthreads();
    float sig3 = spectral_sigma_t<1, 32>(W3, sA, u, v, red);
    float i3 = 1.0f / sig3;
    for (int k = tid; k < 32; k += 256) ws[OFF_W3 + k] = sA[k] * i3;
    return;
  }

  // projection path: stage RAW W1 transposed
  for (int idx = tid; idx < 32 * 257; idx += 256) {
    int j = idx / 257, c = idx - j * 257;
    float w = W1[idx];
    if (c < 128) sA[c * 64 + j] = w;
    else if (c < 256) sA[(c - 128) * 64 + 32 + j] = w;
  }
  __syncthreads();

  __half* p16 = (__half*)(ws + OFF_P16);
  __half* f16 = (__half*)(ws + OFF_F16);
  int nl = tid >> 3;
  int jg = (tid & 7) << 3;
  int slice = (tid & 7);
  int c = blockIdx.x - 1;
  int r0 = c * 64 + nl * 2;
  int r1 = r0 + 1;
  const float4* F0 = (const float4*)&feat[(size_t)r0 * FEATD];
  const float4* F1 = (const float4*)&feat[(size_t)r1 * FEATD];
  float acc0[8] = {0,0,0,0,0,0,0,0};
  float acc1[8] = {0,0,0,0,0,0,0,0};
  #pragma unroll 2
  for (int k4 = 0; k4 < 32; ++k4) {
    float4 f0 = F0[k4];
    float4 f1 = F1[k4];
    if (doF16 && (k4 >> 2) == slice) {
      U32H2 a, b;
      uint2 pk;
      a.h[0] = (_Float16)f0.x; a.h[1] = (_Float16)f0.y; pk.x = a.u;
      b.h[0] = (_Float16)f0.z; b.h[1] = (_Float16)f0.w; pk.y = b.u;
      *(uint2*)((char*)f16 + (size_t)r0 * 256 + (size_t)k4 * 8) = pk;
      a.h[0] = (_Float16)f1.x; a.h[1] = (_Float16)f1.y; pk.x = a.u;
      b.h[0] = (_Float16)f1.z; b.h[1] = (_Float16)f1.w; pk.y = b.u;
      *(uint2*)((char*)f16 + (size_t)r1 * 256 + (size_t)k4 * 8) = pk;
    }
    #pragma unroll
    for (int kk = 0; kk < 4; ++kk) {
      int k = 4 * k4 + kk;
      float fv0 = (kk == 0) ? f0.x : (kk == 1) ? f0.y : (kk == 2) ? f0.z : f0.w;
      float fv1 = (kk == 0) ? f1.x : (kk == 1) ? f1.y : (kk == 2) ? f1.z : f1.w;
      float4 w0 = *(const float4*)&sA[k * 64 + jg];
      float4 w1 = *(const float4*)&sA[k * 64 + jg + 4];
      acc0[0] += fv0 * w0.x; acc0[1] += fv0 * w0.y; acc0[2] += fv0 * w0.z; acc0[3] += fv0 * w0.w;
      acc0[4] += fv0 * w1.x; acc0[5] += fv0 * w1.y; acc0[6] += fv0 * w1.z; acc0[7] += fv0 * w1.w;
      acc1[0] += fv1 * w0.x; acc1[1] += fv1 * w0.y; acc1[2] += fv1 * w0.z; acc1[3] += fv1 * w0.w;
      acc1[4] += fv1 * w1.x; acc1[5] += fv1 * w1.y; acc1[6] += fv1 * w1.z; acc1[7] += fv1 * w1.w;
    }
  }
  U32H2 t0, t1, t2, t3;
  uint4 o;
  t0.h[0]=(_Float16)acc0[0]; t0.h[1]=(_Float16)acc0[1];
  t1.h[0]=(_Float16)acc0[2]; t1.h[1]=(_Float16)acc0[3];
  t2.h[0]=(_Float16)acc0[4]; t2.h[1]=(_Float16)acc0[5];
  t3.h[0]=(_Float16)acc0[6]; t3.h[1]=(_Float16)acc0[7];
  o.x=t0.u; o.y=t1.u; o.z=t2.u; o.w=t3.u;
  *(uint4*)((char*)p16 + (size_t)r0 * 128 + (size_t)jg * 2) = o;
  t0.h[0]=(_Float16)acc1[0]; t0.h[1]=(_Float16)acc1[1];
  t1.h[0]=(_Float16)acc1[2]; t1.h[1]=(_Float16)acc1[3];
  t2.h[0]=(_Float16)acc1[4]; t2.h[1]=(_Float16)acc1[5];
  t3.h[0]=(_Float16)acc1[6]; t3.h[1]=(_Float16)acc1[7];
  o.x=t0.u; o.y=t1.u; o.z=t2.u; o.w=t3.u;
  *(uint4*)((char*)p16 + (size_t)r1 * 128 + (size_t)jg * 2) = o;
}

// ---------------- bucket sort by batch (3 passes) ----------------
__global__ __launch_bounds__(256) void bucket_count(const int* __restrict__ bids,
                                                    int* __restrict__ wsI, int E) {
  __shared__ int cnt[4];
  int tid = threadIdx.x;
  if (tid < 4) cnt[tid] = 0;
  __syncthreads();
  int chunk = (E + 255) / 256;
  int cs = blockIdx.x * chunk;
  int ce = min(cs + chunk, E);
  for (int i = cs + tid; i < ce; i += 256) atomicAdd(&cnt[bids[i]], 1);
  __syncthreads();
  if (tid < 4) wsI[OFF_BC + blockIdx.x * 4 + tid] = cnt[tid];
}

__global__ __launch_bounds__(256) void bucket_scan(int* __restrict__ wsI, int E) {
  __shared__ int A[1024], B[1024];
  int tid = threadIdx.x;
  for (int i = tid; i < 1024; i += 256) {
    int blk = i & 255, b = i >> 8;       // batch-major: i = b*256 + blk
    A[i] = wsI[OFF_BC + blk * 4 + b];
  }
  __syncthreads();
  int* s = A; int* d = B;
  for (int off = 1; off < 1024; off <<= 1) {
    for (int i = tid; i < 1024; i += 256)
      d[i] = s[i] + ((i >= off) ? s[i - off] : 0);
    __syncthreads();
    int* t = s; s = d; d = t;
  }
  // s = inclusive scan
  for (int i = tid; i < 1024; i += 256) {
    int excl = i ? s[i - 1] : 0;
    int blk = i & 255, b = i >> 8;
    wsI[OFF_BASE + blk * 4 + b] = excl;
  }
  if (tid < 4) wsI[OFF_SEG + tid] = tid ? s[tid * 256 - 1] : 0;
  if (tid == 4) wsI[OFF_SEG + 4] = s[1023];
}

__global__ __launch_bounds__(256) void bucket_scatter(const int* __restrict__ bids,
                                                      const int* __restrict__ srcs,
                                                      const int* __restrict__ tgts,
                                                      int* __restrict__ wsI, int E) {
  __shared__ int cur[4];
  int tid = threadIdx.x;
  if (tid < 4) cur[tid] = wsI[OFF_BASE + blockIdx.x * 4 + tid];
  __syncthreads();
  int chunk = (E + 255) / 256;
  int cs = blockIdx.x * chunk;
  int ce = min(cs + chunk, E);
  int4* rec = (int4*)(wsI + OFF_REC);
  for (int i = cs + tid; i < ce; i += 256) {
    int b = bids[i];
    int pos = atomicAdd(&cur[b], 1);
    rec[pos] = make_int4(b * NNODES + srcs[i], b * NNODES + tgts[i], i, 0);
  }
}

// ---------------- edge kernel helpers ----------------
__device__ __forceinline__ float grp_dist_f16(uint4 au, uint4 bu) {
  U4H2 a, b; a.u = au; b.u = bu;
  float ssd = 0.f;
  #pragma unroll
  for (int p = 0; p < 4; ++p) { h2 d = a.h[p] - b.h[p]; ssd = fdot2f(d, d, ssd); }
  ssd += __shfl_xor(ssd, 1, 64);
  ssd += __shfl_xor(ssd, 2, 64);
  ssd += __shfl_xor(ssd, 4, 64);
  ssd += __shfl_xor(ssd, 8, 64);
  return sqrtf(ssd);
}

__device__ __forceinline__ unsigned h1pack(unsigned puv, unsigned quv, float dist, float i1,
                                           float w1l0, float w1l1, float bb0, float bb1) {
  U32H2 p, q; p.u = puv; q.u = quv;
  float h0  = fmaxf(fmaf((float)p.h[0] + (float)q.h[0], i1, fmaf(dist, w1l0, bb0)), 0.f);
  float h1v = fmaxf(fmaf((float)p.h[1] + (float)q.h[1], i1, fmaf(dist, w1l1, bb1)), 0.f);
  U32H2 r; r.h[0] = (_Float16)h0; r.h[1] = (_Float16)h1v;
  return r.u;
}

// ---------------- batch-segmented edge kernel (records path) ----------------
__global__ __launch_bounds__(256, 8) void edge_seg(const float* __restrict__ ws,
                                                   const float* __restrict__ b1,
                                                   const float* __restrict__ b2,
                                                   const float* __restrict__ b3,
                                                   float* __restrict__ out, int E, int bi) {
  __shared__ unsigned ht[256 * 17];
  __shared__ int sRS[256], sRT[256];
  int tid = threadIdx.x;
  int lane = tid & 15;
  int grp  = tid >> 4;

  const int* wsI = (const int*)ws;
  const __half* feat16 = (const __half*)(ws + OFF_F16);
  const __half* p16    = (const __half*)(ws + OFF_P16);
  const unsigned* w2h  = (const unsigned*)(ws + OFF_W2H);
  const int4* rec = (const int4*)(wsI + OFF_REC);

  int start = wsI[OFF_SEG + bi];
  int end   = wsI[OFF_SEG + bi + 1];

  float i1 = ws[OFF_I1];
  int j0 = 2 * lane;
  float w1l0 = ws[OFF_W1L + j0];
  float w1l1 = ws[OFF_W1L + j0 + 1];
  float bb0  = b1[j0];
  float bb1  = b1[j0 + 1];
  float bias3 = b3[0];

  for (int base = start + blockIdx.x * 256; base < end; base += gridDim.x * 256) {
    int n = min(256, end - base);
    int4 r = make_int4(0, 0, 0, 0);
    if (tid < n) {
      r = rec[base + tid];
      sRS[tid] = r.x;
      sRT[tid] = r.y;
    }
    __syncthreads();

    if (n == 256) {
      #pragma unroll 1
      for (int rr = 0; rr < 8; ++rr) {
        int el0 = (rr * 2 + 0) * 16 + grp;
        int el1 = (rr * 2 + 1) * 16 + grp;
        int rs0 = sRS[el0], rt0 = sRT[el0];
        int rs1 = sRS[el1], rt1 = sRT[el1];
        uint4 a0 = *(const uint4*)((const char*)feat16 + ((size_t)rs0 << 8) + (lane << 4));
        uint4 c0 = *(const uint4*)((const char*)feat16 + ((size_t)rt0 << 8) + (lane << 4));
        uint4 a1 = *(const uint4*)((const char*)feat16 + ((size_t)rs1 << 8) + (lane << 4));
        uint4 c1 = *(const uint4*)((const char*)feat16 + ((size_t)rt1 << 8) + (lane << 4));
        unsigned pu0 = *(const unsigned*)((const char*)p16 + ((size_t)rs0 << 7) + (lane << 2));
        unsigned qu0 = *(const unsigned*)((const char*)p16 + ((size_t)rt0 << 7) + 64 + (lane << 2));
        unsigned pu1 = *(const unsigned*)((const char*)p16 + ((size_t)rs1 << 7) + (lane << 2));
        unsigned qu1 = *(const unsigned*)((const char*)p16 + ((size_t)rt1 << 7) + 64 + (lane << 2));
        float d0 = grp_dist_f16(a0, c0);
        float d1 = grp_dist_f16(a1, c1);
        ht[el0 * 17 + lane] = h1pack(pu0, qu0, d0, i1, w1l0, w1l1, bb0, bb1);
        ht[el1 * 17 + lane] = h1pack(pu1, qu1, d1, i1, w1l0, w1l1, bb0, bb1);
      }
    } else {
      #pragma unroll 2
      for (int rr = 0; rr < 16; ++rr) {
        int el = rr * 16 + grp;
        if (el < n) {
          int rs = sRS[el], rt = sRT[el];
          uint4 au = *(const uint4*)((const char*)feat16 + ((size_t)rs << 8) + (lane << 4));
          uint4 bu = *(const uint4*)((const char*)feat16 + ((size_t)rt << 8) + (lane << 4));
          float dist = grp_dist_f16(au, bu);
          unsigned puv = *(const unsigned*)((const char*)p16 + ((size_t)rs << 7) + (lane << 2));
          unsigned quv = *(const unsigned*)((const char*)p16 + ((size_t)rt << 7) + 64 + (lane << 2));
          ht[el * 17 + lane] = h1pack(puv, quv, dist, i1, w1l0, w1l1, bb0, bb1);
        }
      }
    }
    __syncthreads();

    if (tid < n) {
      unsigned hrow[16];
      #pragma unroll
      for (int q = 0; q < 16; ++q) hrow[q] = ht[tid * 17 + q];
      float la = bias3;
      #pragma unroll
      for (int j = 0; j < 32; ++j) {
        float acc = b2[j];
        #pragma unroll
        for (int q = 0; q < 16; ++q) {
          U32H2 w; w.u = w2h[j * 16 + q];
          U32H2 h; h.u = hrow[q];
          acc = fdot2f(w.h, h.h, acc);
        }
        la += ws[OFF_W3 + j] * fmaxf(acc, 0.f);
      }
      la = fminf(fmaxf(la, -5.f), 5.f);
      out[r.z]     = 1.0f / (1.0f + exp2f(la * -2.18590179f));
      out[E + r.z] = la;
    }
    __syncthreads();
  }
}

// ---------------- R5 fallback edge kernel (unsorted) ----------------
template <bool F16>
__global__ __launch_bounds__(256, 8) void edge_fused(const float* __restrict__ feat,
                                                     const float* __restrict__ ws,
                                                     const float* __restrict__ b1,
                                                     const float* __restrict__ b2,
                                                     const float* __restrict__ b3,
                                                     const int* __restrict__ bids,
                                                     const int* __restrict__ srcs,
                                                     const int* __restrict__ tgts,
                                                     float* __restrict__ out, int E) {
  __shared__ unsigned ht[256 * 17];
  __shared__ int sRS[256], sRT[256];
  int tid = threadIdx.x;
  int lane = tid & 15;
  int grp  = tid >> 4;

  const __half* feat16 = (const __half*)(ws + OFF_F16);
  const __half* p16    = (const __half*)(ws + OFF_P16);
  const unsigned* w2h  = (const unsigned*)(ws + OFF_W2H);

  float i1 = ws[OFF_I1];
  int j0 = 2 * lane;
  float w1l0 = ws[OFF_W1L + j0];
  float w1l1 = ws[OFF_W1L + j0 + 1];
  float bb0  = b1[j0];
  float bb1  = b1[j0 + 1];
  float bias3 = b3[0];

  for (int base = blockIdx.x * 256; base < E; base += gridDim.x * 256) {
    int e0 = base + tid;
    if (e0 < E) {
      int b = bids[e0];
      sRS[tid] = b * NNODES + srcs[e0];
      sRT[tid] = b * NNODES + tgts[e0];
    }
    __syncthreads();

    if (F16 && (base + 256 <= E)) {
      #pragma unroll 1
      for (int rr = 0; rr < 8; ++rr) {
        int el0 = (rr * 2 + 0) * 16 + grp;
        int el1 = (rr * 2 + 1) * 16 + grp;
        int rs0 = sRS[el0], rt0 = sRT[el0];
        int rs1 = sRS[el1], rt1 = sRT[el1];
        uint4 a0 = *(const uint4*)((const char*)feat16 + ((size_t)rs0 << 8) + (lane << 4));
        uint4 c0 = *(const uint4*)((const char*)feat16 + ((size_t)rt0 << 8) + (lane << 4));
        uint4 a1 = *(const uint4*)((const char*)feat16 + ((size_t)rs1 << 8) + (lane << 4));
        uint4 c1 = *(const uint4*)((const char*)feat16 + ((size_t)rt1 << 8) + (lane << 4));
        unsigned pu0 = *(const unsigned*)((const char*)p16 + ((size_t)rs0 << 7) + (lane << 2));
        unsigned qu0 = *(const unsigned*)((const char*)p16 + ((size_t)rt0 << 7) + 64 + (lane << 2));
        unsigned pu1 = *(const unsigned*)((const char*)p16 + ((size_t)rs1 << 7) + (lane << 2));
        unsigned qu1 = *(const unsigned*)((const char*)p16 + ((size_t)rt1 << 7) + 64 + (lane << 2));
        float d0 = grp_dist_f16(a0, c0);
        float d1 = grp_dist_f16(a1, c1);
        ht[el0 * 17 + lane] = h1pack(pu0, qu0, d0, i1, w1l0, w1l1, bb0, bb1);
        ht[el1 * 17 + lane] = h1pack(pu1, qu1, d1, i1, w1l0, w1l1, bb0, bb1);
      }
    } else {
      #pragma unroll 2
      for (int rr = 0; rr < 16; ++rr) {
        int el = rr * 16 + grp;
        int e  = base + el;
        if (e < E) {
          int rs = sRS[el], rt = sRT[el];
          float dist;
          if (F16) {
            uint4 au = *(const uint4*)((const char*)feat16 + ((size_t)rs << 8) + (lane << 4));
            uint4 bu = *(const uint4*)((const char*)feat16 + ((size_t)rt << 8) + (lane << 4));
            dist = grp_dist_f16(au, bu);
          } else {
            const float4* A  = (const float4*)&feat[(size_t)rs * FEATD];
            const float4* Bp = (const float4*)&feat[(size_t)rt * FEATD];
            float ssd = 0.f;
            #pragma unroll
            for (int p = 0; p < 2; ++p) {
              float4 a = A[lane * 2 + p], c = Bp[lane * 2 + p];
              float dx = a.x - c.x, dy = a.y - c.y, dz = a.z - c.z, dw = a.w - c.w;
              ssd += dx * dx + dy * dy + dz * dz + dw * dw;
            }
            ssd += __shfl_xor(ssd, 1, 64);
            ssd += __shfl_xor(ssd, 2, 64);
            ssd += __shfl_xor(ssd, 4, 64);
            ssd += __shfl_xor(ssd, 8, 64);
            dist = sqrtf(ssd);
          }
          unsigned puv = *(const unsigned*)((const char*)p16 + ((size_t)rs << 7) + (lane << 2));
          unsigned quv = *(const unsigned*)((const char*)p16 + ((size_t)rt << 7) + 64 + (lane << 2));
          ht[el * 17 + lane] = h1pack(puv, quv, dist, i1, w1l0, w1l1, bb0, bb1);
        }
      }
    }
    __syncthreads();

    int e = base + tid;
    if (e < E) {
      unsigned hrow[16];
      #pragma unroll
      for (int q = 0; q < 16; ++q) hrow[q] = ht[tid * 17 + q];
      float la = bias3;
      #pragma unroll
      for (int j = 0; j < 32; ++j) {
        float acc = b2[j];
        #pragma unroll
        for (int q = 0; q < 16; ++q) {
          U32H2 w; w.u = w2h[j * 16 + q];
          U32H2 h; h.u = hrow[q];
          acc = fdot2f(w.h, h.h, acc);
        }
        la += ws[OFF_W3 + j] * fmaxf(acc, 0.f);
      }
      la = fminf(fmaxf(la, -5.f), 5.f);
      out[e]     = 1.0f / (1.0f + exp2f(la * -2.18590179f));
      out[E + e] = la;
    }
    __syncthreads();
  }
}

// ---------------- tiny-ws fallback: full spectral + in-loop W1, all f32 ----------------
__global__ __launch_bounds__(256) void spectral_full(const float* __restrict__ W1,
                                                     const float* __restrict__ W2,
                                                     const float* __restrict__ W3,
                                                     float* __restrict__ ws) {
  __shared__ float sA[32 * 257];
  __shared__ float u[32], v[257];
  __shared__ float red[8];
  int tid = threadIdx.x;
  float sig1 = spectral_sigma_t<32, 257>(W1, sA, u, v, red);
  float i1 = 1.0f / sig1;
  for (int idx = tid; idx < 128 * 64; idx += 256) {
    int k = idx >> 6, jj = idx & 63;
    float w = (jj < 32) ? sA[jj * 257 + k] : sA[(jj - 32) * 257 + 128 + k];
    ws[OFF_FBWT + idx] = w * i1;
  }
  for (int j = tid; j < 32; j += 256) ws[OFF_W1L + j] = sA[j * 257 + 256] * i1;
  __syncthreads();
  float sig2 = spectral_sigma_t<32, 32>(W2, sA, u, v, red);
  float i2 = 1.0f / sig2;
  for (int idx = tid; idx < 1024; idx += 256) ws[OFF_W2 + idx] = sA[idx] * i2;
  __syncthreads();
  float sig3 = spectral_sigma_t<1, 32>(W3, sA, u, v, red);
  float i3 = 1.0f / sig3;
  for (int k = tid; k < 32; k += 256) ws[OFF_W3 + k] = sA[k] * i3;
}

__global__ __launch_bounds__(256) void edge_kernel_nop(const float* __restrict__ feat,
                                                       const float* __restrict__ ws,
                                                       const float* __restrict__ b1,
                                                       const float* __restrict__ b2,
                                                       const float* __restrict__ b3,
                                                       const int* __restrict__ bids,
                                                       const int* __restrict__ srcs,
                                                       const int* __restrict__ tgts,
                                                       float* __restrict__ out, int E) {
  __shared__ float sWt[128 * 64];
  __shared__ float sW2[1024];
  __shared__ float sW3[32], sW1l[32], sB1[32], sB2[32];
  int tid = threadIdx.x;
  for (int i = tid * 4; i < 128 * 64; i += 256 * 4)
    *(float4*)&sWt[i] = *(const float4*)&ws[OFF_FBWT + i];
  for (int i = tid; i < 1024; i += 256) sW2[i] = ws[OFF_W2 + i];
  if (tid < 32) {
    sW3[tid]  = ws[OFF_W3 + tid];
    sW1l[tid] = ws[OFF_W1L + tid];
    sB1[tid]  = b1[tid];
    sB2[tid]  = b2[tid];
  }
  __syncthreads();
  float bias3 = b3[0];

  for (int e = blockIdx.x * 256 + tid; e < E; e += gridDim.x * 256) {
    int b = bids[e], s = srcs[e], t = tgts[e];
    const float4* A  = (const float4*)&feat[(size_t)(b * NNODES + s) * FEATD];
    const float4* Bp = (const float4*)&feat[(size_t)(b * NNODES + t) * FEATD];
    float ssd = 0.f;
    float h1p[32];
    #pragma unroll
    for (int j = 0; j < 32; ++j) h1p[j] = 0.f;
    #pragma unroll 1
    for (int k4 = 0; k4 < 32; ++k4) {
      float4 a = A[k4], c = Bp[k4];
      float dx = a.x - c.x, dy = a.y - c.y, dz = a.z - c.z, dw = a.w - c.w;
      ssd += dx * dx + dy * dy + dz * dz + dw * dw;
      #pragma unroll
      for (int kk = 0; kk < 4; ++kk) {
        int k = 4 * k4 + kk;
        float fa = (kk == 0) ? a.x : (kk == 1) ? a.y : (kk == 2) ? a.z : a.w;
        float fc = (kk == 0) ? c.x : (kk == 1) ? c.y : (kk == 2) ? c.z : c.w;
        #pragma unroll
        for (int q = 0; q < 8; ++q) {
          float4 w0 = *(const float4*)&sWt[k * 64 + 4 * q];
          float4 w1 = *(const float4*)&sWt[k * 64 + 32 + 4 * q];
          h1p[4*q+0] += fa * w0.x + fc * w1.x;
          h1p[4*q+1] += fa * w0.y + fc * w1.y;
          h1p[4*q+2] += fa * w0.z + fc * w1.z;
          h1p[4*q+3] += fa * w0.w + fc * w1.w;
        }
      }
    }
    float dist = sqrtf(ssd);
    float h1[32];
    #pragma unroll
    for (int j = 0; j < 32; ++j)
      h1[j] = fmaxf(h1p[j] + dist * sW1l[j] + sB1[j], 0.f);
    float la = bias3;
    #pragma unroll
    for (int j = 0; j < 32; ++j) {
      float acc = sB2[j];
      #pragma unroll
      for (int q = 0; q < 8; ++q) {
        float4 w = *(const float4*)&sW2[j * 32 + 4 * q];
        acc += w.x * h1[4 * q] + w.y * h1[4 * q + 1] + w.z * h1[4 * q + 2] + w.w * h1[4 * q + 3];
      }
      la += sW3[j] * fmaxf(acc, 0.f);
    }
    la = fminf(fmaxf(la, -5.f), 5.f);
    out[e]     = 1.0f / (1.0f + __expf(-la / 0.66f));
    out[E + e] = la;
  }
}

extern "C" void kernel_launch(void* const* d_in, const int* in_sizes, int n_in,
                              void* d_out, int out_size, void* d_ws, size_t ws_size,
                              hipStream_t stream) {
  const float* feat = (const float*)d_in[0];
  const float* W1   = (const float*)d_in[1];
  const float* b1   = (const float*)d_in[2];
  const float* W2   = (const float*)d_in[3];
  const float* b2   = (const float*)d_in[4];
  const float* W3   = (const float*)d_in[5];
  const float* b3   = (const float*)d_in[6];
  const int* bids   = (const int*)d_in[7];
  const int* srcs   = (const int*)d_in[8];
  const int* tgts   = (const int*)d_in[9];
  float* out = (float*)d_out;
  float* ws  = (float*)d_ws;
  int* wsI   = (int*)d_ws;
  int E = in_sizes[7];

  size_t need_p   = (size_t)OFF_F16 * sizeof(float);
  size_t need_f16 = (size_t)(OFF_F16 + F16_FLOATS) * sizeof(float);
  size_t need_rec = ((size_t)OFF_REC + (size_t)E * 4) * sizeof(float);
  int egrid = (E + 255) / 256;

  if (ws_size >= need_rec) {
    prep_kernel<<<dim3(626), dim3(256), 0, stream>>>(feat, W1, W2, W3, ws, 1);
    bucket_count<<<dim3(256), dim3(256), 0, stream>>>(bids, wsI, E);
    bucket_scan<<<dim3(1), dim3(256), 0, stream>>>(wsI, E);
    bucket_scatter<<<dim3(256), dim3(256), 0, stream>>>(bids, srcs, tgts, wsI, E);
    int gseg = (E / 4 + 8192 + 255) / 256;
    for (int bi = 0; bi < 4; ++bi)
      edge_seg<<<dim3(gseg), dim3(256), 0, stream>>>(ws, b1, b2, b3, out, E, bi);
  } else if (ws_size >= need_f16) {
    prep_kernel<<<dim3(626), dim3(256), 0, stream>>>(feat, W1, W2, W3, ws, 1);
    edge_fused<true><<<dim3(egrid), dim3(256), 0, stream>>>(feat, ws, b1, b2, b3,
                                                            bids, srcs, tgts, out, E);
  } else if (ws_size >= need_p) {
    prep_kernel<<<dim3(626), dim3(256), 0, stream>>>(feat, W1, W2, W3, ws, 0);
    edge_fused<false><<<dim3(egrid), dim3(256), 0, stream>>>(feat, ws, b1, b2, b3,
                                                             bids, srcs, tgts, out, E);
  } else {
    spectral_full<<<dim3(1), dim3(256), 0, stream>>>(W1, W2, W3, ws);
    edge_kernel_nop<<<dim3(egrid), dim3(256), 0, stream>>>(feat, ws, b1, b2, b3,
                                                           bids, srcs, tgts, out, E);
  }
}

// Round 7
// 108.179 us; speedup vs baseline: 1.4309x; 1.4309x over previous
//
#include <hip/hip_runtime.h>
#include <hip/hip_fp16.h>
#include <math.h>

#define FEATD 128
#define NNODES 10000
#define NBATCH 4
#define NROWS (NBATCH*NNODES)   // 40000

// ws layout (float slots, 4B each)
#define OFF_I1   0                     // 1/sigma1
#define OFF_W1L  8                     // w1last normalized [32] f32
#define OFF_W2   64                    // W2 normalized [32*32] f32 (fallback)
#define OFF_W3   1088                  // W3 normalized [32] f32
#define OFF_W2H  1120                  // W2 normalized half2 [512 uint slots]
#define OFF_P16  4096                  // P16 raw proj [40000][64] half (5.12 MB)
#define P16_FLOATS (NROWS*64/2)        // 1,280,000 float slots
#define OFF_F16  (OFF_P16 + P16_FLOATS) // feat16 [40000][128] half (10.24 MB)
#define F16_FLOATS (NROWS*FEATD/2)     // 2,560,000 float slots
#define OFF_FBWT OFF_P16               // fallback: normalized Wt[128][64] f32

typedef _Float16 h2 __attribute__((ext_vector_type(2)));
union U32H2 { unsigned u; h2 h; };
union U4H2  { uint4 u; h2 h[4]; };

#if defined(__has_builtin)
#if __has_builtin(__builtin_amdgcn_fdot2)
#define HAVE_FDOT2 1
#endif
#endif

__device__ __forceinline__ float fdot2f(h2 a, h2 b, float c) {
#ifdef HAVE_FDOT2
  return __builtin_amdgcn_fdot2(a, b, c, false);
#else
  return c + (float)a[0] * (float)b[0] + (float)a[1] * (float)b[1];
#endif
}

// ------------- spectral sigma: exact reference power iteration, 2 barriers/iter -------------
template <int M, int K>
__device__ float spectral_sigma_t(const float* __restrict__ Wg,
                                  float* sW, float* u, float* v, volatile float* red) {
  int tid = threadIdx.x;
  int wid = tid >> 6, lid = tid & 63;
  int j8 = tid >> 3, l8 = tid & 7;
  for (int i = tid; i < M * K; i += 256) sW[i] = Wg[i];
  if (tid < M) u[tid] = 1.0f;
  __syncthreads();
  float invu = 1.0f / sqrtf((float)M);
  float invv = 0.f;

  for (int it = 0; it < 5; ++it) {
    float p = 0.f;
    for (int k = tid; k < K; k += 256) {
      float a = 0.f;
      #pragma unroll
      for (int j = 0; j < M; ++j) a += sW[j * K + k] * u[j];
      a *= invu;
      v[k] = a;
      p += a * a;
    }
    #pragma unroll
    for (int off = 1; off < 64; off <<= 1) p += __shfl_xor(p, off, 64);
    if (lid == 0) red[wid] = p;
    __syncthreads();
    p = red[0] + red[1] + red[2] + red[3];
    invv = 1.0f / (sqrtf(p) + 1e-12f);

    float a = 0.f;
    if (j8 < M) {
      #pragma unroll
      for (int k = l8; k < K; k += 8) a += sW[j8 * K + k] * v[k];
      a *= invv;
    }
    a += __shfl_xor(a, 1, 64);
    a += __shfl_xor(a, 2, 64);
    a += __shfl_xor(a, 4, 64);
    float q = 0.f;
    if (j8 < M && l8 == 0) { u[j8] = a; q = a * a; }
    #pragma unroll
    for (int off = 1; off < 64; off <<= 1) q += __shfl_xor(q, off, 64);
    if (lid == 0) red[4 + wid] = q;
    __syncthreads();
    q = red[4] + red[5] + red[6] + red[7];
    invu = 1.0f / (sqrtf(q) + 1e-12f);
  }

  float a = 0.f;
  if (j8 < M) {
    #pragma unroll
    for (int k = l8; k < K; k += 8) a += sW[j8 * K + k] * v[k];
  }
  a += __shfl_xor(a, 1, 64);
  a += __shfl_xor(a, 2, 64);
  a += __shfl_xor(a, 4, 64);
  float s = (j8 < M && l8 == 0) ? a * u[j8] : 0.f;
  #pragma unroll
  for (int off = 1; off < 64; off <<= 1) s += __shfl_xor(s, off, 64);
  if (lid == 0) red[wid] = s;
  __syncthreads();
  float sig = (red[0] + red[1] + red[2] + red[3]) * invu * invv;
  __syncthreads();
  return sig;
}

// ---------------- fused prep kernel ----------------
// block 0:      spectral norm -> ws (i1, w1l_n, W2n f32, W2n half2, W3n)
// blocks 1..625: P16 projection with RAW W1, 4 rows/thread, 4-wide jg; f16 copy folded in.
__global__ __launch_bounds__(256, 4) void prep_kernel(const float* __restrict__ feat,
                                                      const float* __restrict__ W1,
                                                      const float* __restrict__ W2,
                                                      const float* __restrict__ W3,
                                                      float* __restrict__ ws,
                                                      int doF16) {
  __shared__ float sA[32 * 257];
  __shared__ float u[32], v[257];
  __shared__ float red[8];
  int tid = threadIdx.x;

  if (blockIdx.x == 0) {
    float sig1 = spectral_sigma_t<32, 257>(W1, sA, u, v, red);
    float i1 = 1.0f / sig1;
    if (tid == 0) ws[OFF_I1] = i1;
    for (int j = tid; j < 32; j += 256) ws[OFF_W1L + j] = sA[j * 257 + 256] * i1;
    __syncthreads();
    float sig2 = spectral_sigma_t<32, 32>(W2, sA, u, v, red);
    float i2 = 1.0f / sig2;
    for (int idx = tid; idx < 1024; idx += 256) ws[OFF_W2 + idx] = sA[idx] * i2;
    unsigned* w2h = (unsigned*)(ws + OFF_W2H);
    for (int idx = tid; idx < 512; idx += 256) {
      int j = idx >> 4, q = idx & 15;
      U32H2 pk;
      pk.h[0] = (_Float16)(sA[j * 32 + 2 * q] * i2);
      pk.h[1] = (_Float16)(sA[j * 32 + 2 * q + 1] * i2);
      w2h[idx] = pk.u;
    }
    __syncthreads();
    float sig3 = spectral_sigma_t<1, 32>(W3, sA, u, v, red);
    float i3 = 1.0f / sig3;
    for (int k = tid; k < 32; k += 256) ws[OFF_W3 + k] = sA[k] * i3;
    return;
  }

  // stage RAW W1 transposed: sA[k*64+j] = W1[j][k] (j<32), sA[k*64+32+j] = W1[j][128+k]
  for (int idx = tid; idx < 32 * 257; idx += 256) {
    int j = idx / 257, c = idx - j * 257;
    float w = W1[idx];
    if (c < 128) sA[c * 64 + j] = w;
    else if (c < 256) sA[(c - 128) * 64 + 32 + j] = w;
  }
  __syncthreads();

  __half* p16 = (__half*)(ws + OFF_P16);
  __half* f16 = (__half*)(ws + OFF_F16);
  int rg = tid >> 4;              // 0..15 row group
  int jg = (tid & 15) << 2;       // 0,4,...,60 output slice (4 wide)
  int slice = tid & 15;           // owns k4 in {2*slice, 2*slice+1} for f16 write
  int r0 = (blockIdx.x - 1) * 64 + rg * 4;   // 625*64 = 40000 exact
  const float4* F0 = (const float4*)&feat[(size_t)(r0 + 0) * FEATD];
  const float4* F1 = (const float4*)&feat[(size_t)(r0 + 1) * FEATD];
  const float4* F2 = (const float4*)&feat[(size_t)(r0 + 2) * FEATD];
  const float4* F3 = (const float4*)&feat[(size_t)(r0 + 3) * FEATD];
  float acc[4][4] = {{0,0,0,0},{0,0,0,0},{0,0,0,0},{0,0,0,0}};

  #pragma unroll 2
  for (int k4 = 0; k4 < 32; ++k4) {
    float4 f0 = F0[k4], f1 = F1[k4], f2 = F2[k4], f3 = F3[k4];
    if (doF16 && (k4 >> 1) == slice) {
      U32H2 a, b; uint2 pk;
      a.h[0]=(_Float16)f0.x; a.h[1]=(_Float16)f0.y; b.h[0]=(_Float16)f0.z; b.h[1]=(_Float16)f0.w;
      pk.x=a.u; pk.y=b.u; *(uint2*)((char*)f16 + (size_t)(r0+0)*256 + (size_t)k4*8) = pk;
      a.h[0]=(_Float16)f1.x; a.h[1]=(_Float16)f1.y; b.h[0]=(_Float16)f1.z; b.h[1]=(_Float16)f1.w;
      pk.x=a.u; pk.y=b.u; *(uint2*)((char*)f16 + (size_t)(r0+1)*256 + (size_t)k4*8) = pk;
      a.h[0]=(_Float16)f2.x; a.h[1]=(_Float16)f2.y; b.h[0]=(_Float16)f2.z; b.h[1]=(_Float16)f2.w;
      pk.x=a.u; pk.y=b.u; *(uint2*)((char*)f16 + (size_t)(r0+2)*256 + (size_t)k4*8) = pk;
      a.h[0]=(_Float16)f3.x; a.h[1]=(_Float16)f3.y; b.h[0]=(_Float16)f3.z; b.h[1]=(_Float16)f3.w;
      pk.x=a.u; pk.y=b.u; *(uint2*)((char*)f16 + (size_t)(r0+3)*256 + (size_t)k4*8) = pk;
    }
    #pragma unroll
    for (int kk = 0; kk < 4; ++kk) {
      int k = 4 * k4 + kk;
      float4 w = *(const float4*)&sA[k * 64 + jg];
      float e0 = (kk == 0) ? f0.x : (kk == 1) ? f0.y : (kk == 2) ? f0.z : f0.w;
      float e1 = (kk == 0) ? f1.x : (kk == 1) ? f1.y : (kk == 2) ? f1.z : f1.w;
      float e2 = (kk == 0) ? f2.x : (kk == 1) ? f2.y : (kk == 2) ? f2.z : f2.w;
      float e3 = (kk == 0) ? f3.x : (kk == 1) ? f3.y : (kk == 2) ? f3.z : f3.w;
      acc[0][0] += e0 * w.x; acc[0][1] += e0 * w.y; acc[0][2] += e0 * w.z; acc[0][3] += e0 * w.w;
      acc[1][0] += e1 * w.x; acc[1][1] += e1 * w.y; acc[1][2] += e1 * w.z; acc[1][3] += e1 * w.w;
      acc[2][0] += e2 * w.x; acc[2][1] += e2 * w.y; acc[2][2] += e2 * w.z; acc[2][3] += e2 * w.w;
      acc[3][0] += e3 * w.x; acc[3][1] += e3 * w.y; acc[3][2] += e3 * w.z; acc[3][3] += e3 * w.w;
    }
  }
  #pragma unroll
  for (int r = 0; r < 4; ++r) {
    U32H2 a, b;
    a.h[0] = (_Float16)acc[r][0]; a.h[1] = (_Float16)acc[r][1];
    b.h[0] = (_Float16)acc[r][2]; b.h[1] = (_Float16)acc[r][3];
    uint2 o; o.x = a.u; o.y = b.u;
    *(uint2*)((char*)p16 + (size_t)(r0 + r) * 128 + (size_t)jg * 2) = o;
  }
}

// ---------------- edge kernel helpers ----------------
__device__ __forceinline__ float grp_dist_f16(uint4 au, uint4 bu) {
  U4H2 a, b; a.u = au; b.u = bu;
  float ssd = 0.f;
  #pragma unroll
  for (int p = 0; p < 4; ++p) { h2 d = a.h[p] - b.h[p]; ssd = fdot2f(d, d, ssd); }
  ssd += __shfl_xor(ssd, 1, 64);
  ssd += __shfl_xor(ssd, 2, 64);
  ssd += __shfl_xor(ssd, 4, 64);
  ssd += __shfl_xor(ssd, 8, 64);
  return sqrtf(ssd);
}

__device__ __forceinline__ unsigned h1pack(unsigned puv, unsigned quv, float dist, float i1,
                                           float w1l0, float w1l1, float bb0, float bb1) {
  U32H2 p, q; p.u = puv; q.u = quv;
  float h0  = fmaxf(fmaf((float)p.h[0] + (float)q.h[0], i1, fmaf(dist, w1l0, bb0)), 0.f);
  float h1v = fmaxf(fmaf((float)p.h[1] + (float)q.h[1], i1, fmaf(dist, w1l1, bb1)), 0.f);
  U32H2 r; r.h[0] = (_Float16)h0; r.h[1] = (_Float16)h1v;
  return r.u;
}

// ---------------- fused edge kernel (R5 structure) ----------------
template <bool F16>
__global__ __launch_bounds__(256, 8) void edge_fused(const float* __restrict__ feat,
                                                     const float* __restrict__ ws,
                                                     const float* __restrict__ b1,
                                                     const float* __restrict__ b2,
                                                     const float* __restrict__ b3,
                                                     const int* __restrict__ bids,
                                                     const int* __restrict__ srcs,
                                                     const int* __restrict__ tgts,
                                                     float* __restrict__ out, int E) {
  __shared__ unsigned ht[256 * 17];
  __shared__ int sRS[256], sRT[256];
  int tid = threadIdx.x;
  int lane = tid & 15;
  int grp  = tid >> 4;

  const __half* feat16 = (const __half*)(ws + OFF_F16);
  const __half* p16    = (const __half*)(ws + OFF_P16);
  const unsigned* w2h  = (const unsigned*)(ws + OFF_W2H);

  float i1 = ws[OFF_I1];
  int j0 = 2 * lane;
  float w1l0 = ws[OFF_W1L + j0];
  float w1l1 = ws[OFF_W1L + j0 + 1];
  float bb0  = b1[j0];
  float bb1  = b1[j0 + 1];
  float bias3 = b3[0];

  for (int base = blockIdx.x * 256; base < E; base += gridDim.x * 256) {
    int e0 = base + tid;
    if (e0 < E) {
      int b = bids[e0];
      sRS[tid] = b * NNODES + srcs[e0];
      sRT[tid] = b * NNODES + tgts[e0];
    }
    __syncthreads();

    if (F16 && (base + 256 <= E)) {
      #pragma unroll 1
      for (int rr = 0; rr < 8; ++rr) {
        int el0 = (rr * 2 + 0) * 16 + grp;
        int el1 = (rr * 2 + 1) * 16 + grp;
        int rs0 = sRS[el0], rt0 = sRT[el0];
        int rs1 = sRS[el1], rt1 = sRT[el1];
        uint4 a0 = *(const uint4*)((const char*)feat16 + ((size_t)rs0 << 8) + (lane << 4));
        uint4 c0 = *(const uint4*)((const char*)feat16 + ((size_t)rt0 << 8) + (lane << 4));
        uint4 a1 = *(const uint4*)((const char*)feat16 + ((size_t)rs1 << 8) + (lane << 4));
        uint4 c1 = *(const uint4*)((const char*)feat16 + ((size_t)rt1 << 8) + (lane << 4));
        unsigned pu0 = *(const unsigned*)((const char*)p16 + ((size_t)rs0 << 7) + (lane << 2));
        unsigned qu0 = *(const unsigned*)((const char*)p16 + ((size_t)rt0 << 7) + 64 + (lane << 2));
        unsigned pu1 = *(const unsigned*)((const char*)p16 + ((size_t)rs1 << 7) + (lane << 2));
        unsigned qu1 = *(const unsigned*)((const char*)p16 + ((size_t)rt1 << 7) + 64 + (lane << 2));
        float d0 = grp_dist_f16(a0, c0);
        float d1 = grp_dist_f16(a1, c1);
        ht[el0 * 17 + lane] = h1pack(pu0, qu0, d0, i1, w1l0, w1l1, bb0, bb1);
        ht[el1 * 17 + lane] = h1pack(pu1, qu1, d1, i1, w1l0, w1l1, bb0, bb1);
      }
    } else {
      #pragma unroll 2
      for (int rr = 0; rr < 16; ++rr) {
        int el = rr * 16 + grp;
        int e  = base + el;
        if (e < E) {
          int rs = sRS[el], rt = sRT[el];
          float dist;
          if (F16) {
            uint4 au = *(const uint4*)((const char*)feat16 + ((size_t)rs << 8) + (lane << 4));
            uint4 bu = *(const uint4*)((const char*)feat16 + ((size_t)rt << 8) + (lane << 4));
            dist = grp_dist_f16(au, bu);
          } else {
            const float4* A  = (const float4*)&feat[(size_t)rs * FEATD];
            const float4* Bp = (const float4*)&feat[(size_t)rt * FEATD];
            float ssd = 0.f;
            #pragma unroll
            for (int p = 0; p < 2; ++p) {
              float4 a = A[lane * 2 + p], c = Bp[lane * 2 + p];
              float dx = a.x - c.x, dy = a.y - c.y, dz = a.z - c.z, dw = a.w - c.w;
              ssd += dx * dx + dy * dy + dz * dz + dw * dw;
            }
            ssd += __shfl_xor(ssd, 1, 64);
            ssd += __shfl_xor(ssd, 2, 64);
            ssd += __shfl_xor(ssd, 4, 64);
            ssd += __shfl_xor(ssd, 8, 64);
            dist = sqrtf(ssd);
          }
          unsigned puv = *(const unsigned*)((const char*)p16 + ((size_t)rs << 7) + (lane << 2));
          unsigned quv = *(const unsigned*)((const char*)p16 + ((size_t)rt << 7) + 64 + (lane << 2));
          ht[el * 17 + lane] = h1pack(puv, quv, dist, i1, w1l0, w1l1, bb0, bb1);
        }
      }
    }
    __syncthreads();

    int e = base + tid;
    if (e < E) {
      unsigned hrow[16];
      #pragma unroll
      for (int q = 0; q < 16; ++q) hrow[q] = ht[tid * 17 + q];
      float la = bias3;
      #pragma unroll
      for (int j = 0; j < 32; ++j) {
        float acc = b2[j];
        #pragma unroll
        for (int q = 0; q < 16; ++q) {
          U32H2 w; w.u = w2h[j * 16 + q];
          U32H2 h; h.u = hrow[q];
          acc = fdot2f(w.h, h.h, acc);
        }
        la += ws[OFF_W3 + j] * fmaxf(acc, 0.f);
      }
      la = fminf(fmaxf(la, -5.f), 5.f);
      out[e]     = 1.0f / (1.0f + exp2f(la * -2.18590179f));
      out[E + e] = la;
    }
    __syncthreads();
  }
}

// ---------------- tiny-ws fallback: full spectral + in-loop W1, all f32 ----------------
__global__ __launch_bounds__(256) void spectral_full(const float* __restrict__ W1,
                                                     const float* __restrict__ W2,
                                                     const float* __restrict__ W3,
                                                     float* __restrict__ ws) {
  __shared__ float sA[32 * 257];
  __shared__ float u[32], v[257];
  __shared__ float red[8];
  int tid = threadIdx.x;
  float sig1 = spectral_sigma_t<32, 257>(W1, sA, u, v, red);
  float i1 = 1.0f / sig1;
  for (int idx = tid; idx < 128 * 64; idx += 256) {
    int k = idx >> 6, jj = idx & 63;
    float w = (jj < 32) ? sA[jj * 257 + k] : sA[(jj - 32) * 257 + 128 + k];
    ws[OFF_FBWT + idx] = w * i1;
  }
  for (int j = tid; j < 32; j += 256) ws[OFF_W1L + j] = sA[j * 257 + 256] * i1;
  __syncthreads();
  float sig2 = spectral_sigma_t<32, 32>(W2, sA, u, v, red);
  float i2 = 1.0f / sig2;
  for (int idx = tid; idx < 1024; idx += 256) ws[OFF_W2 + idx] = sA[idx] * i2;
  __syncthreads();
  float sig3 = spectral_sigma_t<1, 32>(W3, sA, u, v, red);
  float i3 = 1.0f / sig3;
  for (int k = tid; k < 32; k += 256) ws[OFF_W3 + k] = sA[k] * i3;
}

__global__ __launch_bounds__(256) void edge_kernel_nop(const float* __restrict__ feat,
                                                       const float* __restrict__ ws,
                                                       const float* __restrict__ b1,
                                                       const float* __restrict__ b2,
                                                       const float* __restrict__ b3,
                                                       const int* __restrict__ bids,
                                                       const int* __restrict__ srcs,
                                                       const int* __restrict__ tgts,
                                                       float* __restrict__ out, int E) {
  __shared__ float sWt[128 * 64];
  __shared__ float sW2[1024];
  __shared__ float sW3[32], sW1l[32], sB1[32], sB2[32];
  int tid = threadIdx.x;
  for (int i = tid * 4; i < 128 * 64; i += 256 * 4)
    *(float4*)&sWt[i] = *(const float4*)&ws[OFF_FBWT + i];
  for (int i = tid; i < 1024; i += 256) sW2[i] = ws[OFF_W2 + i];
  if (tid < 32) {
    sW3[tid]  = ws[OFF_W3 + tid];
    sW1l[tid] = ws[OFF_W1L + tid];
    sB1[tid]  = b1[tid];
    sB2[tid]  = b2[tid];
  }
  __syncthreads();
  float bias3 = b3[0];

  for (int e = blockIdx.x * 256 + tid; e < E; e += gridDim.x * 256) {
    int b = bids[e], s = srcs[e], t = tgts[e];
    const float4* A  = (const float4*)&feat[(size_t)(b * NNODES + s) * FEATD];
    const float4* Bp = (const float4*)&feat[(size_t)(b * NNODES + t) * FEATD];
    float ssd = 0.f;
    float h1p[32];
    #pragma unroll
    for (int j = 0; j < 32; ++j) h1p[j] = 0.f;
    #pragma unroll 1
    for (int k4 = 0; k4 < 32; ++k4) {
      float4 a = A[k4], c = Bp[k4];
      float dx = a.x - c.x, dy = a.y - c.y, dz = a.z - c.z, dw = a.w - c.w;
      ssd += dx * dx + dy * dy + dz * dz + dw * dw;
      #pragma unroll
      for (int kk = 0; kk < 4; ++kk) {
        int k = 4 * k4 + kk;
        float fa = (kk == 0) ? a.x : (kk == 1) ? a.y : (kk == 2) ? a.z : a.w;
        float fc = (kk == 0) ? c.x : (kk == 1) ? c.y : (kk == 2) ? c.z : c.w;
        #pragma unroll
        for (int q = 0; q < 8; ++q) {
          float4 w0 = *(const float4*)&sWt[k * 64 + 4 * q];
          float4 w1 = *(const float4*)&sWt[k * 64 + 32 + 4 * q];
          h1p[4*q+0] += fa * w0.x + fc * w1.x;
          h1p[4*q+1] += fa * w0.y + fc * w1.y;
          h1p[4*q+2] += fa * w0.z + fc * w1.z;
          h1p[4*q+3] += fa * w0.w + fc * w1.w;
        }
      }
    }
    float dist = sqrtf(ssd);
    float h1[32];
    #pragma unroll
    for (int j = 0; j < 32; ++j)
      h1[j] = fmaxf(h1p[j] + dist * sW1l[j] + sB1[j], 0.f);
    float la = bias3;
    #pragma unroll
    for (int j = 0; j < 32; ++j) {
      float acc = sB2[j];
      #pragma unroll
      for (int q = 0; q < 8; ++q) {
        float4 w = *(const float4*)&sW2[j * 32 + 4 * q];
        acc += w.x * h1[4 * q] + w.y * h1[4 * q + 1] + w.z * h1[4 * q + 2] + w.w * h1[4 * q + 3];
      }
      la += sW3[j] * fmaxf(acc, 0.f);
    }
    la = fminf(fmaxf(la, -5.f), 5.f);
    out[e]     = 1.0f / (1.0f + __expf(-la / 0.66f));
    out[E + e] = la;
  }
}

extern "C" void kernel_launch(void* const* d_in, const int* in_sizes, int n_in,
                              void* d_out, int out_size, void* d_ws, size_t ws_size,
                              hipStream_t stream) {
  const float* feat = (const float*)d_in[0];
  const float* W1   = (const float*)d_in[1];
  const float* b1   = (const float*)d_in[2];
  const float* W2   = (const float*)d_in[3];
  const float* b2   = (const float*)d_in[4];
  const float* W3   = (const float*)d_in[5];
  const float* b3   = (const float*)d_in[6];
  const int* bids   = (const int*)d_in[7];
  const int* srcs   = (const int*)d_in[8];
  const int* tgts   = (const int*)d_in[9];
  float* out = (float*)d_out;
  float* ws  = (float*)d_ws;
  int E = in_sizes[7];

  size_t need_p   = (size_t)OFF_F16 * sizeof(float);                 // P16 only
  size_t need_f16 = (size_t)(OFF_F16 + F16_FLOATS) * sizeof(float);  // + feat16
  int egrid = (E + 255) / 256;

  if (ws_size >= need_f16) {
    prep_kernel<<<dim3(626), dim3(256), 0, stream>>>(feat, W1, W2, W3, ws, 1);
    edge_fused<true><<<dim3(egrid), dim3(256), 0, stream>>>(feat, ws, b1, b2, b3,
                                                            bids, srcs, tgts, out, E);
  } else if (ws_size >= need_p) {
    prep_kernel<<<dim3(626), dim3(256), 0, stream>>>(feat, W1, W2, W3, ws, 0);
    edge_fused<false><<<dim3(egrid), dim3(256), 0, stream>>>(feat, ws, b1, b2, b3,
                                                             bids, srcs, tgts, out, E);
  } else {
    spectral_full<<<dim3(1), dim3(256), 0, stream>>>(W1, W2, W3, ws);
    edge_kernel_nop<<<dim3(egrid), dim3(256), 0, stream>>>(feat, ws, b1, b2, b3,
                                                           bids, srcs, tgts, out, E);
  }
}

// Round 8
// 103.005 us; speedup vs baseline: 1.5028x; 1.0502x over previous
//
#include <hip/hip_runtime.h>
#include <hip/hip_fp16.h>
#include <math.h>

#define FEATD 128
#define NNODES 10000
#define NBATCH 4
#define NROWS (NBATCH*NNODES)   // 40000

// ws layout (float slots, 4B each)
#define OFF_I1   0                     // 1/sigma1
#define OFF_W1L  8                     // w1last normalized [32] f32
#define OFF_W2   64                    // W2 normalized [32*32] f32 (fallback)
#define OFF_W3   1088                  // W3 normalized [32] f32
#define OFF_W2H  1120                  // W2 normalized half2 [512 uint slots]
#define OFF_P16  4096                  // P16 raw proj [40000][64] half (5.12 MB)
#define P16_FLOATS (NROWS*64/2)        // 1,280,000 float slots
#define OFF_F16  (OFF_P16 + P16_FLOATS) // feat16 [40000][128] half (10.24 MB)
#define F16_FLOATS (NROWS*FEATD/2)     // 2,560,000 float slots
#define OFF_FBWT OFF_P16               // fallback: normalized Wt[128][64] f32

#define WSTRIDE 68                     // padded k-row stride (bank-conflict fix)

typedef _Float16 h2 __attribute__((ext_vector_type(2)));
union U32H2 { unsigned u; h2 h; };
union U4H2  { uint4 u; h2 h[4]; };

#if defined(__has_builtin)
#if __has_builtin(__builtin_amdgcn_fdot2)
#define HAVE_FDOT2 1
#endif
#endif

__device__ __forceinline__ float fdot2f(h2 a, h2 b, float c) {
#ifdef HAVE_FDOT2
  return __builtin_amdgcn_fdot2(a, b, c, false);
#else
  return c + (float)a[0] * (float)b[0] + (float)a[1] * (float)b[1];
#endif
}

// ------------- spectral sigma: exact reference power iteration, 2 barriers/iter -------------
template <int M, int K>
__device__ float spectral_sigma_t(const float* __restrict__ Wg,
                                  float* sW, float* u, float* v, volatile float* red) {
  int tid = threadIdx.x;
  int wid = tid >> 6, lid = tid & 63;
  int j8 = tid >> 3, l8 = tid & 7;
  for (int i = tid; i < M * K; i += 256) sW[i] = Wg[i];
  if (tid < M) u[tid] = 1.0f;
  __syncthreads();
  float invu = 1.0f / sqrtf((float)M);
  float invv = 0.f;

  for (int it = 0; it < 5; ++it) {
    float p = 0.f;
    for (int k = tid; k < K; k += 256) {
      float a = 0.f;
      #pragma unroll
      for (int j = 0; j < M; ++j) a += sW[j * K + k] * u[j];
      a *= invu;
      v[k] = a;
      p += a * a;
    }
    #pragma unroll
    for (int off = 1; off < 64; off <<= 1) p += __shfl_xor(p, off, 64);
    if (lid == 0) red[wid] = p;
    __syncthreads();
    p = red[0] + red[1] + red[2] + red[3];
    invv = 1.0f / (sqrtf(p) + 1e-12f);

    float a = 0.f;
    if (j8 < M) {
      #pragma unroll
      for (int k = l8; k < K; k += 8) a += sW[j8 * K + k] * v[k];
      a *= invv;
    }
    a += __shfl_xor(a, 1, 64);
    a += __shfl_xor(a, 2, 64);
    a += __shfl_xor(a, 4, 64);
    float q = 0.f;
    if (j8 < M && l8 == 0) { u[j8] = a; q = a * a; }
    #pragma unroll
    for (int off = 1; off < 64; off <<= 1) q += __shfl_xor(q, off, 64);
    if (lid == 0) red[4 + wid] = q;
    __syncthreads();
    q = red[4] + red[5] + red[6] + red[7];
    invu = 1.0f / (sqrtf(q) + 1e-12f);
  }

  float a = 0.f;
  if (j8 < M) {
    #pragma unroll
    for (int k = l8; k < K; k += 8) a += sW[j8 * K + k] * v[k];
  }
  a += __shfl_xor(a, 1, 64);
  a += __shfl_xor(a, 2, 64);
  a += __shfl_xor(a, 4, 64);
  float s = (j8 < M && l8 == 0) ? a * u[j8] : 0.f;
  #pragma unroll
  for (int off = 1; off < 64; off <<= 1) s += __shfl_xor(s, off, 64);
  if (lid == 0) red[wid] = s;
  __syncthreads();
  float sig = (red[0] + red[1] + red[2] + red[3]) * invu * invv;
  __syncthreads();
  return sig;
}

// ---------------- fused prep kernel ----------------
// block 0:      spectral norm -> ws (i1, w1l_n, W2n f32, W2n half2, W3n)
// blocks 1..625: P16 projection with RAW W1, 4 rows/thread, padded LDS (no bank conflicts)
__global__ __launch_bounds__(256, 4) void prep_kernel(const float* __restrict__ feat,
                                                      const float* __restrict__ W1,
                                                      const float* __restrict__ W2,
                                                      const float* __restrict__ W3,
                                                      float* __restrict__ ws,
                                                      int doF16) {
  __shared__ float sA[128 * WSTRIDE];   // 34.8 KB; block 0 uses first 32*257=8224 floats
  __shared__ float u[32], v[257];
  __shared__ float red[8];
  int tid = threadIdx.x;

  if (blockIdx.x == 0) {
    float sig1 = spectral_sigma_t<32, 257>(W1, sA, u, v, red);
    float i1 = 1.0f / sig1;
    if (tid == 0) ws[OFF_I1] = i1;
    for (int j = tid; j < 32; j += 256) ws[OFF_W1L + j] = sA[j * 257 + 256] * i1;
    __syncthreads();
    float sig2 = spectral_sigma_t<32, 32>(W2, sA, u, v, red);
    float i2 = 1.0f / sig2;
    for (int idx = tid; idx < 1024; idx += 256) ws[OFF_W2 + idx] = sA[idx] * i2;
    unsigned* w2h = (unsigned*)(ws + OFF_W2H);
    for (int idx = tid; idx < 512; idx += 256) {
      int j = idx >> 4, q = idx & 15;
      U32H2 pk;
      pk.h[0] = (_Float16)(sA[j * 32 + 2 * q] * i2);
      pk.h[1] = (_Float16)(sA[j * 32 + 2 * q + 1] * i2);
      w2h[idx] = pk.u;
    }
    __syncthreads();
    float sig3 = spectral_sigma_t<1, 32>(W3, sA, u, v, red);
    float i3 = 1.0f / sig3;
    for (int k = tid; k < 32; k += 256) ws[OFF_W3 + k] = sA[k] * i3;
    return;
  }

  // stage RAW W1 transposed with padded stride:
  //   sA[k*WSTRIDE + j]      = W1[j][k]        (k<128, j<32)   [src half]
  //   sA[k*WSTRIDE + 32 + j] = W1[j][128+k]                    [tgt half]
  for (int idx = tid; idx < 32 * 257; idx += 256) {
    int j = idx / 257, c = idx - j * 257;
    float w = W1[idx];
    if (c < 128) sA[c * WSTRIDE + j] = w;
    else if (c < 256) sA[(c - 128) * WSTRIDE + 32 + j] = w;
  }
  __syncthreads();

  __half* p16 = (__half*)(ws + OFF_P16);
  __half* f16 = (__half*)(ws + OFF_F16);
  int rg = tid >> 4;              // 0..15 row group
  int jg = (tid & 15) << 2;       // 0,4,...,60 output slice (4 wide)
  int slice = tid & 15;           // owns k4 in {2*slice, 2*slice+1} for f16 write
  int r0 = (blockIdx.x - 1) * 64 + rg * 4;   // 625*64 = 40000 exact
  const float4* F0 = (const float4*)&feat[(size_t)(r0 + 0) * FEATD];
  const float4* F1 = (const float4*)&feat[(size_t)(r0 + 1) * FEATD];
  const float4* F2 = (const float4*)&feat[(size_t)(r0 + 2) * FEATD];
  const float4* F3 = (const float4*)&feat[(size_t)(r0 + 3) * FEATD];
  float acc[4][4] = {{0,0,0,0},{0,0,0,0},{0,0,0,0},{0,0,0,0}};

  #pragma unroll 2
  for (int k4 = 0; k4 < 32; ++k4) {
    float4 f0 = F0[k4], f1 = F1[k4], f2 = F2[k4], f3 = F3[k4];
    if (doF16 && (k4 >> 1) == slice) {
      U32H2 a, b; uint2 pk;
      a.h[0]=(_Float16)f0.x; a.h[1]=(_Float16)f0.y; b.h[0]=(_Float16)f0.z; b.h[1]=(_Float16)f0.w;
      pk.x=a.u; pk.y=b.u; *(uint2*)((char*)f16 + (size_t)(r0+0)*256 + (size_t)k4*8) = pk;
      a.h[0]=(_Float16)f1.x; a.h[1]=(_Float16)f1.y; b.h[0]=(_Float16)f1.z; b.h[1]=(_Float16)f1.w;
      pk.x=a.u; pk.y=b.u; *(uint2*)((char*)f16 + (size_t)(r0+1)*256 + (size_t)k4*8) = pk;
      a.h[0]=(_Float16)f2.x; a.h[1]=(_Float16)f2.y; b.h[0]=(_Float16)f2.z; b.h[1]=(_Float16)f2.w;
      pk.x=a.u; pk.y=b.u; *(uint2*)((char*)f16 + (size_t)(r0+2)*256 + (size_t)k4*8) = pk;
      a.h[0]=(_Float16)f3.x; a.h[1]=(_Float16)f3.y; b.h[0]=(_Float16)f3.z; b.h[1]=(_Float16)f3.w;
      pk.x=a.u; pk.y=b.u; *(uint2*)((char*)f16 + (size_t)(r0+3)*256 + (size_t)k4*8) = pk;
    }
    #pragma unroll
    for (int kk = 0; kk < 4; ++kk) {
      int k = 4 * k4 + kk;
      float4 w = *(const float4*)&sA[k * WSTRIDE + jg];
      float e0 = (kk == 0) ? f0.x : (kk == 1) ? f0.y : (kk == 2) ? f0.z : f0.w;
      float e1 = (kk == 0) ? f1.x : (kk == 1) ? f1.y : (kk == 2) ? f1.z : f1.w;
      float e2 = (kk == 0) ? f2.x : (kk == 1) ? f2.y : (kk == 2) ? f2.z : f2.w;
      float e3 = (kk == 0) ? f3.x : (kk == 1) ? f3.y : (kk == 2) ? f3.z : f3.w;
      acc[0][0] += e0 * w.x; acc[0][1] += e0 * w.y; acc[0][2] += e0 * w.z; acc[0][3] += e0 * w.w;
      acc[1][0] += e1 * w.x; acc[1][1] += e1 * w.y; acc[1][2] += e1 * w.z; acc[1][3] += e1 * w.w;
      acc[2][0] += e2 * w.x; acc[2][1] += e2 * w.y; acc[2][2] += e2 * w.z; acc[2][3] += e2 * w.w;
      acc[3][0] += e3 * w.x; acc[3][1] += e3 * w.y; acc[3][2] += e3 * w.z; acc[3][3] += e3 * w.w;
    }
  }
  #pragma unroll
  for (int r = 0; r < 4; ++r) {
    U32H2 a, b;
    a.h[0] = (_Float16)acc[r][0]; a.h[1] = (_Float16)acc[r][1];
    b.h[0] = (_Float16)acc[r][2]; b.h[1] = (_Float16)acc[r][3];
    uint2 o; o.x = a.u; o.y = b.u;
    *(uint2*)((char*)p16 + (size_t)(r0 + r) * 128 + (size_t)jg * 2) = o;
  }
}

// ---------------- edge kernel helpers ----------------
__device__ __forceinline__ float grp_dist_f16(uint4 au, uint4 bu) {
  U4H2 a, b; a.u = au; b.u = bu;
  float ssd = 0.f;
  #pragma unroll
  for (int p = 0; p < 4; ++p) { h2 d = a.h[p] - b.h[p]; ssd = fdot2f(d, d, ssd); }
  ssd += __shfl_xor(ssd, 1, 64);
  ssd += __shfl_xor(ssd, 2, 64);
  ssd += __shfl_xor(ssd, 4, 64);
  ssd += __shfl_xor(ssd, 8, 64);
  return sqrtf(ssd);
}

__device__ __forceinline__ unsigned h1pack(unsigned puv, unsigned quv, float dist, float i1,
                                           float w1l0, float w1l1, float bb0, float bb1) {
  U32H2 p, q; p.u = puv; q.u = quv;
  float h0  = fmaxf(fmaf((float)p.h[0] + (float)q.h[0], i1, fmaf(dist, w1l0, bb0)), 0.f);
  float h1v = fmaxf(fmaf((float)p.h[1] + (float)q.h[1], i1, fmaf(dist, w1l1, bb1)), 0.f);
  U32H2 r; r.h[0] = (_Float16)h0; r.h[1] = (_Float16)h1v;
  return r.u;
}

// ---------------- fused edge kernel (R5 structure, unchanged) ----------------
template <bool F16>
__global__ __launch_bounds__(256, 8) void edge_fused(const float* __restrict__ feat,
                                                     const float* __restrict__ ws,
                                                     const float* __restrict__ b1,
                                                     const float* __restrict__ b2,
                                                     const float* __restrict__ b3,
                                                     const int* __restrict__ bids,
                                                     const int* __restrict__ srcs,
                                                     const int* __restrict__ tgts,
                                                     float* __restrict__ out, int E) {
  __shared__ unsigned ht[256 * 17];
  __shared__ int sRS[256], sRT[256];
  int tid = threadIdx.x;
  int lane = tid & 15;
  int grp  = tid >> 4;

  const __half* feat16 = (const __half*)(ws + OFF_F16);
  const __half* p16    = (const __half*)(ws + OFF_P16);
  const unsigned* w2h  = (const unsigned*)(ws + OFF_W2H);

  float i1 = ws[OFF_I1];
  int j0 = 2 * lane;
  float w1l0 = ws[OFF_W1L + j0];
  float w1l1 = ws[OFF_W1L + j0 + 1];
  float bb0  = b1[j0];
  float bb1  = b1[j0 + 1];
  float bias3 = b3[0];

  for (int base = blockIdx.x * 256; base < E; base += gridDim.x * 256) {
    int e0 = base + tid;
    if (e0 < E) {
      int b = bids[e0];
      sRS[tid] = b * NNODES + srcs[e0];
      sRT[tid] = b * NNODES + tgts[e0];
    }
    __syncthreads();

    if (F16 && (base + 256 <= E)) {
      #pragma unroll 1
      for (int rr = 0; rr < 8; ++rr) {
        int el0 = (rr * 2 + 0) * 16 + grp;
        int el1 = (rr * 2 + 1) * 16 + grp;
        int rs0 = sRS[el0], rt0 = sRT[el0];
        int rs1 = sRS[el1], rt1 = sRT[el1];
        uint4 a0 = *(const uint4*)((const char*)feat16 + ((size_t)rs0 << 8) + (lane << 4));
        uint4 c0 = *(const uint4*)((const char*)feat16 + ((size_t)rt0 << 8) + (lane << 4));
        uint4 a1 = *(const uint4*)((const char*)feat16 + ((size_t)rs1 << 8) + (lane << 4));
        uint4 c1 = *(const uint4*)((const char*)feat16 + ((size_t)rt1 << 8) + (lane << 4));
        unsigned pu0 = *(const unsigned*)((const char*)p16 + ((size_t)rs0 << 7) + (lane << 2));
        unsigned qu0 = *(const unsigned*)((const char*)p16 + ((size_t)rt0 << 7) + 64 + (lane << 2));
        unsigned pu1 = *(const unsigned*)((const char*)p16 + ((size_t)rs1 << 7) + (lane << 2));
        unsigned qu1 = *(const unsigned*)((const char*)p16 + ((size_t)rt1 << 7) + 64 + (lane << 2));
        float d0 = grp_dist_f16(a0, c0);
        float d1 = grp_dist_f16(a1, c1);
        ht[el0 * 17 + lane] = h1pack(pu0, qu0, d0, i1, w1l0, w1l1, bb0, bb1);
        ht[el1 * 17 + lane] = h1pack(pu1, qu1, d1, i1, w1l0, w1l1, bb0, bb1);
      }
    } else {
      #pragma unroll 2
      for (int rr = 0; rr < 16; ++rr) {
        int el = rr * 16 + grp;
        int e  = base + el;
        if (e < E) {
          int rs = sRS[el], rt = sRT[el];
          float dist;
          if (F16) {
            uint4 au = *(const uint4*)((const char*)feat16 + ((size_t)rs << 8) + (lane << 4));
            uint4 bu = *(const uint4*)((const char*)feat16 + ((size_t)rt << 8) + (lane << 4));
            dist = grp_dist_f16(au, bu);
          } else {
            const float4* A  = (const float4*)&feat[(size_t)rs * FEATD];
            const float4* Bp = (const float4*)&feat[(size_t)rt * FEATD];
            float ssd = 0.f;
            #pragma unroll
            for (int p = 0; p < 2; ++p) {
              float4 a = A[lane * 2 + p], c = Bp[lane * 2 + p];
              float dx = a.x - c.x, dy = a.y - c.y, dz = a.z - c.z, dw = a.w - c.w;
              ssd += dx * dx + dy * dy + dz * dz + dw * dw;
            }
            ssd += __shfl_xor(ssd, 1, 64);
            ssd += __shfl_xor(ssd, 2, 64);
            ssd += __shfl_xor(ssd, 4, 64);
            ssd += __shfl_xor(ssd, 8, 64);
            dist = sqrtf(ssd);
          }
          unsigned puv = *(const unsigned*)((const char*)p16 + ((size_t)rs << 7) + (lane << 2));
          unsigned quv = *(const unsigned*)((const char*)p16 + ((size_t)rt << 7) + 64 + (lane << 2));
          ht[el * 17 + lane] = h1pack(puv, quv, dist, i1, w1l0, w1l1, bb0, bb1);
        }
      }
    }
    __syncthreads();

    int e = base + tid;
    if (e < E) {
      unsigned hrow[16];
      #pragma unroll
      for (int q = 0; q < 16; ++q) hrow[q] = ht[tid * 17 + q];
      float la = bias3;
      #pragma unroll
      for (int j = 0; j < 32; ++j) {
        float acc = b2[j];
        #pragma unroll
        for (int q = 0; q < 16; ++q) {
          U32H2 w; w.u = w2h[j * 16 + q];
          U32H2 h; h.u = hrow[q];
          acc = fdot2f(w.h, h.h, acc);
        }
        la += ws[OFF_W3 + j] * fmaxf(acc, 0.f);
      }
      la = fminf(fmaxf(la, -5.f), 5.f);
      out[e]     = 1.0f / (1.0f + exp2f(la * -2.18590179f));
      out[E + e] = la;
    }
    __syncthreads();
  }
}

// ---------------- tiny-ws fallback: full spectral + in-loop W1, all f32 ----------------
__global__ __launch_bounds__(256) void spectral_full(const float* __restrict__ W1,
                                                     const float* __restrict__ W2,
                                                     const float* __restrict__ W3,
                                                     float* __restrict__ ws) {
  __shared__ float sA[32 * 257];
  __shared__ float u[32], v[257];
  __shared__ float red[8];
  int tid = threadIdx.x;
  float sig1 = spectral_sigma_t<32, 257>(W1, sA, u, v, red);
  float i1 = 1.0f / sig1;
  for (int idx = tid; idx < 128 * 64; idx += 256) {
    int k = idx >> 6, jj = idx & 63;
    float w = (jj < 32) ? sA[jj * 257 + k] : sA[(jj - 32) * 257 + 128 + k];
    ws[OFF_FBWT + idx] = w * i1;
  }
  for (int j = tid; j < 32; j += 256) ws[OFF_W1L + j] = sA[j * 257 + 256] * i1;
  __syncthreads();
  float sig2 = spectral_sigma_t<32, 32>(W2, sA, u, v, red);
  float i2 = 1.0f / sig2;
  for (int idx = tid; idx < 1024; idx += 256) ws[OFF_W2 + idx] = sA[idx] * i2;
  __syncthreads();
  float sig3 = spectral_sigma_t<1, 32>(W3, sA, u, v, red);
  float i3 = 1.0f / sig3;
  for (int k = tid; k < 32; k += 256) ws[OFF_W3 + k] = sA[k] * i3;
}

__global__ __launch_bounds__(256) void edge_kernel_nop(const float* __restrict__ feat,
                                                       const float* __restrict__ ws,
                                                       const float* __restrict__ b1,
                                                       const float* __restrict__ b2,
                                                       const float* __restrict__ b3,
                                                       const int* __restrict__ bids,
                                                       const int* __restrict__ srcs,
                                                       const int* __restrict__ tgts,
                                                       float* __restrict__ out, int E) {
  __shared__ float sWt[128 * 64];
  __shared__ float sW2[1024];
  __shared__ float sW3[32], sW1l[32], sB1[32], sB2[32];
  int tid = threadIdx.x;
  for (int i = tid * 4; i < 128 * 64; i += 256 * 4)
    *(float4*)&sWt[i] = *(const float4*)&ws[OFF_FBWT + i];
  for (int i = tid; i < 1024; i += 256) sW2[i] = ws[OFF_W2 + i];
  if (tid < 32) {
    sW3[tid]  = ws[OFF_W3 + tid];
    sW1l[tid] = ws[OFF_W1L + tid];
    sB1[tid]  = b1[tid];
    sB2[tid]  = b2[tid];
  }
  __syncthreads();
  float bias3 = b3[0];

  for (int e = blockIdx.x * 256 + tid; e < E; e += gridDim.x * 256) {
    int b = bids[e], s = srcs[e], t = tgts[e];
    const float4* A  = (const float4*)&feat[(size_t)(b * NNODES + s) * FEATD];
    const float4* Bp = (const float4*)&feat[(size_t)(b * NNODES + t) * FEATD];
    float ssd = 0.f;
    float h1p[32];
    #pragma unroll
    for (int j = 0; j < 32; ++j) h1p[j] = 0.f;
    #pragma unroll 1
    for (int k4 = 0; k4 < 32; ++k4) {
      float4 a = A[k4], c = Bp[k4];
      float dx = a.x - c.x, dy = a.y - c.y, dz = a.z - c.z, dw = a.w - c.w;
      ssd += dx * dx + dy * dy + dz * dz + dw * dw;
      #pragma unroll
      for (int kk = 0; kk < 4; ++kk) {
        int k = 4 * k4 + kk;
        float fa = (kk == 0) ? a.x : (kk == 1) ? a.y : (kk == 2) ? a.z : a.w;
        float fc = (kk == 0) ? c.x : (kk == 1) ? c.y : (kk == 2) ? c.z : c.w;
        #pragma unroll
        for (int q = 0; q < 8; ++q) {
          float4 w0 = *(const float4*)&sWt[k * 64 + 4 * q];
          float4 w1 = *(const float4*)&sWt[k * 64 + 32 + 4 * q];
          h1p[4*q+0] += fa * w0.x + fc * w1.x;
          h1p[4*q+1] += fa * w0.y + fc * w1.y;
          h1p[4*q+2] += fa * w0.z + fc * w1.z;
          h1p[4*q+3] += fa * w0.w + fc * w1.w;
        }
      }
    }
    float dist = sqrtf(ssd);
    float h1[32];
    #pragma unroll
    for (int j = 0; j < 32; ++j)
      h1[j] = fmaxf(h1p[j] + dist * sW1l[j] + sB1[j], 0.f);
    float la = bias3;
    #pragma unroll
    for (int j = 0; j < 32; ++j) {
      float acc = sB2[j];
      #pragma unroll
      for (int q = 0; q < 8; ++q) {
        float4 w = *(const float4*)&sW2[j * 32 + 4 * q];
        acc += w.x * h1[4 * q] + w.y * h1[4 * q + 1] + w.z * h1[4 * q + 2] + w.w * h1[4 * q + 3];
      }
      la += sW3[j] * fmaxf(acc, 0.f);
    }
    la = fminf(fmaxf(la, -5.f), 5.f);
    out[e]     = 1.0f / (1.0f + __expf(-la / 0.66f));
    out[E + e] = la;
  }
}

extern "C" void kernel_launch(void* const* d_in, const int* in_sizes, int n_in,
                              void* d_out, int out_size, void* d_ws, size_t ws_size,
                              hipStream_t stream) {
  const float* feat = (const float*)d_in[0];
  const float* W1   = (const float*)d_in[1];
  const float* b1   = (const float*)d_in[2];
  const float* W2   = (const float*)d_in[3];
  const float* b2   = (const float*)d_in[4];
  const float* W3   = (const float*)d_in[5];
  const float* b3   = (const float*)d_in[6];
  const int* bids   = (const int*)d_in[7];
  const int* srcs   = (const int*)d_in[8];
  const int* tgts   = (const int*)d_in[9];
  float* out = (float*)d_out;
  float* ws  = (float*)d_ws;
  int E = in_sizes[7];

  size_t need_p   = (size_t)OFF_F16 * sizeof(float);                 // P16 only
  size_t need_f16 = (size_t)(OFF_F16 + F16_FLOATS) * sizeof(float);  // + feat16
  int egrid = (E + 255) / 256;

  if (ws_size >= need_f16) {
    prep_kernel<<<dim3(626), dim3(256), 0, stream>>>(feat, W1, W2, W3, ws, 1);
    edge_fused<true><<<dim3(egrid), dim3(256), 0, stream>>>(feat, ws, b1, b2, b3,
                                                            bids, srcs, tgts, out, E);
  } else if (ws_size >= need_p) {
    prep_kernel<<<dim3(626), dim3(256), 0, stream>>>(feat, W1, W2, W3, ws, 0);
    edge_fused<false><<<dim3(egrid), dim3(256), 0, stream>>>(feat, ws, b1, b2, b3,
                                                             bids, srcs, tgts, out, E);
  } else {
    spectral_full<<<dim3(1), dim3(256), 0, stream>>>(W1, W2, W3, ws);
    edge_kernel_nop<<<dim3(egrid), dim3(256), 0, stream>>>(feat, ws, b1, b2, b3,
                                                           bids, srcs, tgts, out, E);
  }
}